// Round 1
// baseline (496.078 us; speedup 1.0000x reference)
//
#include <hip/hip_runtime.h>
#include <hip/hip_bf16.h>
#include <cstdint>

// Problem constants (from reference): B=64 graphs, N=512 nodes, H=1024 hidden, E=4 experts.
constexpr int Bc = 64, Nc = 512, Hc = 1024, Ec = 4;
constexpr float EPS = 1e-5f;

typedef __attribute__((ext_vector_type(8))) short bf16x8;
typedef __attribute__((ext_vector_type(4))) float f32x4;
typedef __attribute__((ext_vector_type(4))) unsigned short us4;

__device__ __forceinline__ unsigned short f2b(float f) {
  union { float f; unsigned u; } v; v.f = f;
  unsigned r = v.u + 0x7fffu + ((v.u >> 16) & 1u);   // RNE
  return (unsigned short)(r >> 16);
}
__device__ __forceinline__ float b2f(unsigned short s) {
  union { unsigned u; float f; } v; v.u = ((unsigned)s) << 16;
  return v.f;
}

// ---------------- x: fp32 -> bf16, plus per-(b,h) sums for router mean ----------------
// grid: B*8 blocks, 256 thr. Block handles graph b, 64 rows, all H via float4.
__global__ void k_xconv(const float* __restrict__ x, unsigned short* __restrict__ xb,
                        float* __restrict__ xm) {
  const int b = blockIdx.x >> 3;
  const int n0 = (blockIdx.x & 7) << 6;
  const int t = threadIdx.x;
  size_t base = ((size_t)b * Nc + n0) * Hc + t * 4;
  float s0 = 0.f, s1 = 0.f, s2 = 0.f, s3 = 0.f;
  for (int i = 0; i < 64; ++i) {
    float4 v = *(const float4*)(x + base + (size_t)i * Hc);
    us4 u; u.x = f2b(v.x); u.y = f2b(v.y); u.z = f2b(v.z); u.w = f2b(v.w);
    *(us4*)(xb + base + (size_t)i * Hc) = u;
    s0 += v.x; s1 += v.y; s2 += v.z; s3 += v.w;
  }
  float* p = xm + b * Hc + t * 4;
  atomicAdd(p + 0, s0); atomicAdd(p + 1, s1);
  atomicAdd(p + 2, s2); atomicAdd(p + 3, s3);
}

// ---------------- adj: fp32 -> bf16 ----------------
__global__ void k_adjconv(const float* __restrict__ a, unsigned short* __restrict__ ab) {
  size_t i = ((size_t)blockIdx.x * 256 + threadIdx.x) * 4;
  float4 v = *(const float4*)(a + i);
  us4 u; u.x = f2b(v.x); u.y = f2b(v.y); u.z = f2b(v.z); u.w = f2b(v.w);
  *(us4*)(ab + i) = u;
}

// ---------------- expert_w: fp32 -> bf16 transposed: wT[e][k][h] = w[e][h][k] ----------------
// grid (H/32, H/32, E), block (32,8)
__global__ void k_wtrans(const float* __restrict__ w, unsigned short* __restrict__ wT) {
  __shared__ unsigned short tile[32][33];
  const int e = blockIdx.z;
  const int bx = blockIdx.x * 32;  // input col (k)
  const int by = blockIdx.y * 32;  // input row (h)
  const float* W = w + (size_t)e * Hc * Hc;
  unsigned short* WT = wT + (size_t)e * Hc * Hc;
#pragma unroll
  for (int i = 0; i < 4; ++i) {
    int r = by + threadIdx.y + i * 8;
    tile[threadIdx.y + i * 8][threadIdx.x] = f2b(W[(size_t)r * Hc + bx + threadIdx.x]);
  }
  __syncthreads();
#pragma unroll
  for (int i = 0; i < 4; ++i) {
    int k = bx + threadIdx.y + i * 8;
    WT[(size_t)k * Hc + by + threadIdx.x] = tile[threadIdx.x][threadIdx.y + i * 8];
  }
}

// ---------------- router: scores + argmax ----------------
// grid B blocks, 256 thr
__global__ void k_router(const float* __restrict__ xm, const float* __restrict__ rw,
                         const float* __restrict__ rb, int* __restrict__ top1) {
  const int b = blockIdx.x;
  const int t = threadIdx.x;
  float sc0 = 0, sc1 = 0, sc2 = 0, sc3 = 0;
  const float inv = 1.0f / (float)Nc;
#pragma unroll
  for (int i = 0; i < 4; ++i) {
    int h = t * 4 + i;
    float v = xm[b * Hc + h] * inv;
    sc0 += v * rw[h * 4 + 0]; sc1 += v * rw[h * 4 + 1];
    sc2 += v * rw[h * 4 + 2]; sc3 += v * rw[h * 4 + 3];
  }
#pragma unroll
  for (int off = 1; off < 64; off <<= 1) {
    sc0 += __shfl_xor(sc0, off); sc1 += __shfl_xor(sc1, off);
    sc2 += __shfl_xor(sc2, off); sc3 += __shfl_xor(sc3, off);
  }
  __shared__ float red[4][4];
  const int lane = t & 63, wv = t >> 6;
  if (lane == 0) { red[wv][0] = sc0; red[wv][1] = sc1; red[wv][2] = sc2; red[wv][3] = sc3; }
  __syncthreads();
  if (t == 0) {
    float s[4];
#pragma unroll
    for (int e = 0; e < 4; ++e)
      s[e] = red[0][e] + red[1][e] + red[2][e] + red[3][e] + rb[e];
    int best = 0; float bv = s[0];
#pragma unroll
    for (int e = 1; e < 4; ++e) { if (s[e] > bv) { bv = s[e]; best = e; } }
    top1[b] = best;
  }
}

// ---------------- MFMA GEMM (m97 structure): C[M,Nn] = A[M,K] * Bt[Nn,K]^T ----------------
// 128x128 tile, BK=32, 4 waves (2x2), 16x16x32 bf16 MFMA, global_load_lds staging,
// chunk-XOR swizzle (pre-swizzled global source) to cut ds_read_b128 bank conflicts.
#define GLDS16(g, l) __builtin_amdgcn_global_load_lds( \
    (__attribute__((address_space(1))) const void*)(g), \
    (__attribute__((address_space(3))) void*)(l), 16, 0, 0)

template<bool STATS>
__global__ __launch_bounds__(256, 3) void gemm_bt(
    const unsigned short* __restrict__ Aall, const unsigned short* __restrict__ Btall,
    unsigned short* __restrict__ Call, const int* __restrict__ top1,
    float* __restrict__ ssum, float* __restrict__ ssq,
    int M, int Nn, int K, long aPerB, long btPerB, long cPerB, long aExp)
{
  __shared__ unsigned short As[128 * 32];
  __shared__ unsigned short Bs[128 * 32];
  const int tid = threadIdx.x;
  const int bz = blockIdx.z;
  const unsigned short* A = Aall + (aExp ? (long)top1[bz] * aExp : (long)bz * aPerB);
  const unsigned short* Bt = Btall + (long)bz * btPerB;
  const int m0 = blockIdx.x * 128, n0 = blockIdx.y * 128;

  // staging: thread t loads 16B: row t>>2 (0..63), chunk (t&3) xor-swizzled by row&3
  const int srow = tid >> 2;
  const int schunk = (tid & 3) ^ (srow & 3);
  const unsigned short* aSrc = A + (long)(m0 + srow) * K + schunk * 8;
  const unsigned short* bSrc = Bt + (long)(n0 + srow) * K + schunk * 8;
  unsigned short* ldsA = As + ((tid >> 6) << 9);  // wave-uniform base
  unsigned short* ldsB = Bs + ((tid >> 6) << 9);

  const int lane = tid & 63;
  const int w = tid >> 6;
  const int wr = (w >> 1) * 64, wc = (w & 1) * 64;
  const int fr = lane & 15, fq = lane >> 4;
  const int swz = ((fq ^ (fr & 3)) << 3);  // swizzled chunk offset in ushorts

  f32x4 acc[4][4] = {};

  for (int k0 = 0; k0 < K; k0 += 32) {
    GLDS16(aSrc, ldsA);
    GLDS16(aSrc + (long)64 * K, ldsA + 2048);
    GLDS16(bSrc, ldsB);
    GLDS16(bSrc + (long)64 * K, ldsB + 2048);
    aSrc += 32; bSrc += 32;
    __syncthreads();  // waitcnt vmcnt(0) drains staging; barrier syncs all waves
    bf16x8 af[4], bff[4];
#pragma unroll
    for (int mi = 0; mi < 4; ++mi)
      af[mi] = *(const bf16x8*)(As + (wr + mi * 16 + fr) * 32 + swz);
#pragma unroll
    for (int ni = 0; ni < 4; ++ni)
      bff[ni] = *(const bf16x8*)(Bs + (wc + ni * 16 + fr) * 32 + swz);
#pragma unroll
    for (int mi = 0; mi < 4; ++mi)
#pragma unroll
      for (int ni = 0; ni < 4; ++ni)
        acc[mi][ni] = __builtin_amdgcn_mfma_f32_16x16x32_bf16(af[mi], bff[ni], acc[mi][ni], 0, 0, 0);
    __syncthreads();  // all waves done reading before next tile overwrites
  }

  // epilogue: C[row][col], row = m0+wr+mi*16+fq*4+j, col = n0+wc+ni*16+fr
  unsigned short* C = Call + (long)bz * cPerB;
#pragma unroll
  for (int mi = 0; mi < 4; ++mi) {
#pragma unroll
    for (int ni = 0; ni < 4; ++ni) {
      const int col = n0 + wc + ni * 16 + fr;
      const int rowb = m0 + wr + mi * 16 + fq * 4;
#pragma unroll
      for (int j = 0; j < 4; ++j)
        C[(long)(rowb + j) * Nn + col] = f2b(acc[mi][ni][j]);
    }
  }

  if (STATS) {
    const int e = top1[bz];
#pragma unroll
    for (int ni = 0; ni < 4; ++ni) {
      float s1 = 0.f, s2 = 0.f;
#pragma unroll
      for (int mi = 0; mi < 4; ++mi)
#pragma unroll
        for (int j = 0; j < 4; ++j) { float v = acc[mi][ni][j]; s1 += v; s2 += v * v; }
      s1 += __shfl_xor(s1, 16); s2 += __shfl_xor(s2, 16);
      s1 += __shfl_xor(s1, 32); s2 += __shfl_xor(s2, 32);
      if (fq == 0) {
        const int col = n0 + wc + ni * 16 + fr;
        atomicAdd(&ssum[e * Hc + col], s1);
        atomicAdd(&ssq[e * Hc + col], s2);
      }
    }
  }
}

// ---------------- BN finalize: scale/shift per [E,H] ----------------
__global__ void k_bnfin(const float* __restrict__ ssum, const float* __restrict__ ssq,
                        const int* __restrict__ top1,
                        const float* __restrict__ gamma, const float* __restrict__ beta,
                        float* __restrict__ scale, float* __restrict__ shift) {
  const int i = blockIdx.x * 256 + threadIdx.x;  // E*H = 4096
  const int e = i >> 10;
  int c = 0;
  for (int j = 0; j < Bc; ++j) c += (top1[j] == e) ? 1 : 0;
  float cf = fmaxf((float)c * (float)Nc, 1.0f);
  float mean = ssum[i] / cf;
  float var = ssq[i] / cf - mean * mean;
  float inv = rsqrtf(var + EPS);
  float sc = gamma[i] * inv;
  scale[i] = sc;
  shift[i] = beta[i] - mean * sc;
}

// ---------------- apply BN + ReLU, bf16 -> fp32 out ----------------
__global__ void k_apply(const unsigned short* __restrict__ ob,
                        const float* __restrict__ scale, const float* __restrict__ shift,
                        const int* __restrict__ top1, float* __restrict__ y) {
  size_t idx = ((size_t)blockIdx.x * 256 + threadIdx.x) * 4;
  const int b = (int)(idx >> 19);     // N*H = 2^19
  const int k = (int)(idx & 1023);    // H = 1024
  const int e = top1[b];
  us4 u = *(const us4*)(ob + idx);
  float4 sc = *(const float4*)(scale + e * Hc + k);
  float4 sh = *(const float4*)(shift + e * Hc + k);
  float4 r;
  r.x = fmaxf(fmaf(b2f(u.x), sc.x, sh.x), 0.f);
  r.y = fmaxf(fmaf(b2f(u.y), sc.y, sh.y), 0.f);
  r.z = fmaxf(fmaf(b2f(u.z), sc.z, sh.z), 0.f);
  r.w = fmaxf(fmaf(b2f(u.w), sc.w, sh.w), 0.f);
  *(float4*)(y + idx) = r;
}

extern "C" void kernel_launch(void* const* d_in, const int* in_sizes, int n_in,
                              void* d_out, int out_size, void* d_ws, size_t ws_size,
                              hipStream_t stream) {
  const float* x     = (const float*)d_in[0];
  const float* adj   = (const float*)d_in[1];
  const float* rw    = (const float*)d_in[2];
  const float* rb    = (const float*)d_in[3];
  const float* ew    = (const float*)d_in[4];
  const float* gamma = (const float*)d_in[5];
  const float* beta  = (const float*)d_in[6];
  float* out = (float*)d_out;
  char* ws = (char*)d_ws;

  // workspace layout (bytes)
  float* xm    = (float*)(ws + 0);          // 262144
  float* ssum  = (float*)(ws + 262144);     // 16384
  float* ssq   = (float*)(ws + 278528);     // 16384
  float* scale = (float*)(ws + 294912);     // 16384
  float* shift = (float*)(ws + 311296);     // 16384
  int*   top1  = (int*)  (ws + 327680);     // 256
  unsigned short* xb   = (unsigned short*)(ws + 327936);     // 67108864 (aliased by outb)
  unsigned short* adjb = (unsigned short*)(ws + 67436800);   // 33554432
  unsigned short* wT   = (unsigned short*)(ws + 100991232);  // 8388608
  unsigned short* supT = (unsigned short*)(ws + 109379840);  // 67108864
  unsigned short* outb = xb;  // x_bf16 dead after GEMM1 -> reuse for out_bf16

  hipMemsetAsync(ws, 0, 294912, stream);  // zero xm + ssum + ssq

  k_xconv<<<Bc * 8, 256, 0, stream>>>(x, xb, xm);
  k_adjconv<<<(Bc * Nc * Nc) / 1024, 256, 0, stream>>>(adj, adjb);
  k_wtrans<<<dim3(Hc / 32, Hc / 32, Ec), dim3(32, 8), 0, stream>>>(ew, wT);
  k_router<<<Bc, 256, 0, stream>>>(xm, rw, rb, top1);

  // GEMM1: supT[b][k][n] = sum_h wT[e][k][h] * x[b][n][h];  M=1024, Nn=512, K=1024
  gemm_bt<false><<<dim3(Hc / 128, Nc / 128, Bc), 256, 0, stream>>>(
      wT, xb, supT, top1, nullptr, nullptr,
      Hc, Nc, Hc, 0L, (long)Nc * Hc, (long)Hc * Nc, (long)Hc * Hc);

  // GEMM2: out[b][n][k] = sum_m adj[b][n][m] * supT[b][k][m];  M=512, Nn=1024, K=512
  gemm_bt<true><<<dim3(Nc / 128, Hc / 128, Bc), 256, 0, stream>>>(
      adjb, supT, outb, top1, ssum, ssq,
      Nc, Hc, Nc, (long)Nc * Nc, (long)Hc * Nc, (long)Nc * Hc, 0L);

  k_bnfin<<<(Ec * Hc) / 256, 256, 0, stream>>>(ssum, ssq, top1, gamma, beta, scale, shift);
  k_apply<<<(Bc * Nc * Hc) / 1024, 256, 0, stream>>>(outb, scale, shift, top1, out);
}

// Round 4
// 456.291 us; speedup vs baseline: 1.0872x; 1.0872x over previous
//
#include <hip/hip_runtime.h>
#include <hip/hip_bf16.h>
#include <cstdint>

// Problem constants (from reference): B=64 graphs, N=512 nodes, H=1024 hidden, E=4 experts.
constexpr int Bc = 64, Nc = 512, Hc = 1024, Ec = 4;
constexpr float EPS = 1e-5f;

typedef __attribute__((ext_vector_type(8))) short bf16x8;
typedef __attribute__((ext_vector_type(4))) float f32x4;
typedef __attribute__((ext_vector_type(4))) unsigned short us4;

__device__ __forceinline__ unsigned short f2b(float f) {
  union { float f; unsigned u; } v; v.f = f;
  unsigned r = v.u + 0x7fffu + ((v.u >> 16) & 1u);   // RNE
  return (unsigned short)(r >> 16);
}
__device__ __forceinline__ float b2f(unsigned short s) {
  union { unsigned u; float f; } v; v.u = ((unsigned)s) << 16;
  return v.f;
}

// ---------------- x: fp32 -> bf16, plus per-(b,h) sums for router mean ----------------
__global__ void k_xconv(const float* __restrict__ x, unsigned short* __restrict__ xb,
                        float* __restrict__ xm) {
  const int b = blockIdx.x >> 3;
  const int n0 = (blockIdx.x & 7) << 6;
  const int t = threadIdx.x;
  size_t base = ((size_t)b * Nc + n0) * Hc + t * 4;
  float s0 = 0.f, s1 = 0.f, s2 = 0.f, s3 = 0.f;
  for (int i = 0; i < 64; ++i) {
    float4 v = *(const float4*)(x + base + (size_t)i * Hc);
    us4 u; u.x = f2b(v.x); u.y = f2b(v.y); u.z = f2b(v.z); u.w = f2b(v.w);
    *(us4*)(xb + base + (size_t)i * Hc) = u;
    s0 += v.x; s1 += v.y; s2 += v.z; s3 += v.w;
  }
  float* p = xm + b * Hc + t * 4;
  atomicAdd(p + 0, s0); atomicAdd(p + 1, s1);
  atomicAdd(p + 2, s2); atomicAdd(p + 3, s3);
}

// ---------------- adj: fp32 -> bf16 ----------------
__global__ void k_adjconv(const float* __restrict__ a, unsigned short* __restrict__ ab) {
  size_t i = ((size_t)blockIdx.x * 256 + threadIdx.x) * 4;
  float4 v = *(const float4*)(a + i);
  us4 u; u.x = f2b(v.x); u.y = f2b(v.y); u.z = f2b(v.z); u.w = f2b(v.w);
  *(us4*)(ab + i) = u;
}

// ---------------- expert_w: fp32 -> bf16 transposed: wT[e][k][h] = w[e][h][k] ----------------
__global__ void k_wtrans(const float* __restrict__ w, unsigned short* __restrict__ wT) {
  __shared__ unsigned short tile[32][33];
  const int e = blockIdx.z;
  const int bx = blockIdx.x * 32;
  const int by = blockIdx.y * 32;
  const float* W = w + (size_t)e * Hc * Hc;
  unsigned short* WT = wT + (size_t)e * Hc * Hc;
#pragma unroll
  for (int i = 0; i < 4; ++i) {
    int r = by + threadIdx.y + i * 8;
    tile[threadIdx.y + i * 8][threadIdx.x] = f2b(W[(size_t)r * Hc + bx + threadIdx.x]);
  }
  __syncthreads();
#pragma unroll
  for (int i = 0; i < 4; ++i) {
    int k = bx + threadIdx.y + i * 8;
    WT[(size_t)k * Hc + by + threadIdx.x] = tile[threadIdx.x][threadIdx.y + i * 8];
  }
}

// ---------------- router: scores + argmax ----------------
__global__ void k_router(const float* __restrict__ xm, const float* __restrict__ rw,
                         const float* __restrict__ rb, int* __restrict__ top1) {
  const int b = blockIdx.x;
  const int t = threadIdx.x;
  float sc0 = 0, sc1 = 0, sc2 = 0, sc3 = 0;
  const float inv = 1.0f / (float)Nc;
#pragma unroll
  for (int i = 0; i < 4; ++i) {
    int h = t * 4 + i;
    float v = xm[b * Hc + h] * inv;
    sc0 += v * rw[h * 4 + 0]; sc1 += v * rw[h * 4 + 1];
    sc2 += v * rw[h * 4 + 2]; sc3 += v * rw[h * 4 + 3];
  }
#pragma unroll
  for (int off = 1; off < 64; off <<= 1) {
    sc0 += __shfl_xor(sc0, off); sc1 += __shfl_xor(sc1, off);
    sc2 += __shfl_xor(sc2, off); sc3 += __shfl_xor(sc3, off);
  }
  __shared__ float red[4][4];
  const int lane = t & 63, wv = t >> 6;
  if (lane == 0) { red[wv][0] = sc0; red[wv][1] = sc1; red[wv][2] = sc2; red[wv][3] = sc3; }
  __syncthreads();
  if (t == 0) {
    float s[4];
#pragma unroll
    for (int e = 0; e < 4; ++e)
      s[e] = red[0][e] + red[1][e] + red[2][e] + red[3][e] + rb[e];
    int best = 0; float bv = s[0];
#pragma unroll
    for (int e = 1; e < 4; ++e) { if (s[e] > bv) { bv = s[e]; best = e; } }
    top1[b] = best;
  }
}

// ================= 256x256 8-phase MFMA GEMM: C[M,Nn] = A[M,K] * Bt[Nn,K]^T =================
// BM=BN=256, BK=64, 8 waves (2M x 4N), per-wave 128x64 output, 16x16x32 bf16 MFMA.
// 2 LDS double-buffers (128 KiB), 4 phases/K-tile, counted vmcnt(4) once per K-tile,
// setprio around MFMA clusters, row-XOR chunk swizzle (both-sides), XCD block swizzle.
#define GLDS16(g, l) __builtin_amdgcn_global_load_lds( \
    (__attribute__((address_space(1))) const void*)(g), \
    (__attribute__((address_space(3))) void*)(l), 16, 0, 0)

#define PRE_MFMA() do { \
    __builtin_amdgcn_s_barrier(); \
    asm volatile("s_waitcnt lgkmcnt(0)" ::: "memory"); \
    __builtin_amdgcn_sched_barrier(0); \
    __builtin_amdgcn_s_setprio(1); \
  } while (0)
#define POST_MFMA() do { \
    __builtin_amdgcn_s_setprio(0); \
    __builtin_amdgcn_s_barrier(); \
    __builtin_amdgcn_sched_barrier(0); \
  } while (0)

template<int NX, int NY, bool STATS>
__global__ __launch_bounds__(512, 2) void gemm8(
    const unsigned short* __restrict__ Aall, const unsigned short* __restrict__ Btall,
    unsigned short* __restrict__ Call, const int* __restrict__ top1,
    float* __restrict__ ssum, float* __restrict__ ssq,
    int Nn, int K, long aPerB, long btPerB, long cPerB, long aExp)
{
  static_assert(NX * NY == 8, "grid per graph must be 8 blocks");
  __shared__ char Lds[131072];
#define ALDS(b, h) (Lds + (b) * 65536 + (h) * 16384)
#define BLDS(b, h) (Lds + (b) * 65536 + 32768 + (h) * 16384)

  const int tid = threadIdx.x;
  const int w = tid >> 6, lane = tid & 63;
  const int wm = w >> 2, wn = w & 3;
  const int fr = lane & 15, fq = lane >> 4;

  // XCD-aware bijective block swizzle: 64 consecutive blocks (8 graphs) per XCD chunk.
  const int id = blockIdx.x;
  const int s = (id & 7) * (NX * NY * 8) + (id >> 3);
  const int bz = s >> 3;
  const int r = s & 7;
  const int bx = r % NX, by = r / NX;
  const int m0 = bx * 256, n0 = by * 256;

  const unsigned short* Ag = Aall + (aExp ? (long)top1[bz] * aExp : (long)bz * aPerB);
  const unsigned short* Bg = Btall + (long)bz * btPerB;

  const unsigned short* As0 = Ag + (size_t)m0 * K;
  const unsigned short* As1 = Ag + (size_t)(m0 + 128) * K;
  const unsigned short* Bs0 = Bg + (size_t)n0 * K;
  const unsigned short* Bs1 = Bg + (size_t)(n0 + 128) * K;

  // staging: thread t covers lds 16B-chunks c=tid and c=tid+512 of a 128x64 half-tile
  // (row = c>>3, lds-chunk = c&7). Global source chunk pre-swizzled: g = (c&7)^(row&7)
  // so that lds(row, cc) holds global chunk cc^(row&7)  [both-sides swizzle].
  const int rowA = tid >> 3;                       // 0..63 (2nd GLDS16 covers rowA+64; same &7)
  const int g8 = ((tid & 7) ^ (rowA & 7)) * 8;     // element offset within BK
  const int wb = w << 10;                          // wave-uniform LDS base (w*64*16B)
#define STAGE(slot, src) do { \
    GLDS16((src) + (size_t)rowA * K + g8, (slot) + wb); \
    GLDS16((src) + (size_t)(rowA + 64) * K + g8, (slot) + wb + 8192); \
  } while (0)

  // fragment read addressing: logical chunk kc at byte row*128 + (kc^(row&7))*16
  const int cOff0 = ((fq ^ (fr & 7)) * 16);
  const int cOff1 = cOff0 ^ 64;
  const int bRow0 = (wn & 1) * 64 + fr;            // B row within half (row&7 == fr&7)

  f32x4 acc[8][4] = {};
  const int NT = K >> 6;

  // ---- prologue: tile0 (4 half-tiles) + tile1 A halves; land tile0, keep A(1) in flight
  STAGE(ALDS(0, 0), As0);
  STAGE(ALDS(0, 1), As1);
  STAGE(BLDS(0, 0), Bs0);
  STAGE(BLDS(0, 1), Bs1);
  STAGE(ALDS(1, 0), As0 + 64);
  STAGE(ALDS(1, 1), As1 + 64);
  asm volatile("s_waitcnt vmcnt(4)" ::: "memory");
  __builtin_amdgcn_s_barrier();
  __builtin_amdgcn_sched_barrier(0);

  for (int kt = 0; kt < NT; ++kt) {
    const int bsel = kt & 1;
    const int b1 = bsel ^ 1;                 // buffer of tile kt+1
    const char* aH = ALDS(bsel, wm);
    const char* bH = BLDS(bsel, wn >> 1);
    const int k1 = (kt + 1) << 6, k2 = (kt + 2) << 6;
    bf16x8 Af[8][2]; bf16x8 Bf[4][2];

    // ---- phase 1: stage B-half0(kt+1); read A[0..3], B[0..1]; MFMA quadrant (0,0)
    if (kt + 1 < NT) STAGE(BLDS(b1, 0), Bs0 + k1);
#pragma unroll
    for (int mi = 0; mi < 4; ++mi) {
      Af[mi][0] = *(const bf16x8*)(aH + (mi * 16 + fr) * 128 + cOff0);
      Af[mi][1] = *(const bf16x8*)(aH + (mi * 16 + fr) * 128 + cOff1);
    }
#pragma unroll
    for (int ni = 0; ni < 2; ++ni) {
      Bf[ni][0] = *(const bf16x8*)(bH + (bRow0 + ni * 16) * 128 + cOff0);
      Bf[ni][1] = *(const bf16x8*)(bH + (bRow0 + ni * 16) * 128 + cOff1);
    }
    PRE_MFMA();
#pragma unroll
    for (int mi = 0; mi < 4; ++mi)
#pragma unroll
      for (int ni = 0; ni < 2; ++ni) {
        acc[mi][ni] = __builtin_amdgcn_mfma_f32_16x16x32_bf16(Af[mi][0], Bf[ni][0], acc[mi][ni], 0, 0, 0);
        acc[mi][ni] = __builtin_amdgcn_mfma_f32_16x16x32_bf16(Af[mi][1], Bf[ni][1], acc[mi][ni], 0, 0, 0);
      }
    POST_MFMA();

    // ---- phase 2: stage B-half1(kt+1); read A[4..7]; MFMA quadrant (1,0)
    if (kt + 1 < NT) STAGE(BLDS(b1, 1), Bs1 + k1);
#pragma unroll
    for (int mi = 4; mi < 8; ++mi) {
      Af[mi][0] = *(const bf16x8*)(aH + (mi * 16 + fr) * 128 + cOff0);
      Af[mi][1] = *(const bf16x8*)(aH + (mi * 16 + fr) * 128 + cOff1);
    }
    PRE_MFMA();
#pragma unroll
    for (int mi = 4; mi < 8; ++mi)
#pragma unroll
      for (int ni = 0; ni < 2; ++ni) {
        acc[mi][ni] = __builtin_amdgcn_mfma_f32_16x16x32_bf16(Af[mi][0], Bf[ni][0], acc[mi][ni], 0, 0, 0);
        acc[mi][ni] = __builtin_amdgcn_mfma_f32_16x16x32_bf16(Af[mi][1], Bf[ni][1], acc[mi][ni], 0, 0, 0);
      }
    POST_MFMA();

    // ---- phase 3: stage A-half0(kt+2) (A(kt) reads finished in ph2); read B[2..3]; MFMA (0,1)
    if (kt + 2 < NT) STAGE(ALDS(bsel, 0), As0 + k2);
#pragma unroll
    for (int ni = 2; ni < 4; ++ni) {
      Bf[ni][0] = *(const bf16x8*)(bH + (bRow0 + ni * 16) * 128 + cOff0);
      Bf[ni][1] = *(const bf16x8*)(bH + (bRow0 + ni * 16) * 128 + cOff1);
    }
    PRE_MFMA();
#pragma unroll
    for (int mi = 0; mi < 4; ++mi)
#pragma unroll
      for (int ni = 2; ni < 4; ++ni) {
        acc[mi][ni] = __builtin_amdgcn_mfma_f32_16x16x32_bf16(Af[mi][0], Bf[ni][0], acc[mi][ni], 0, 0, 0);
        acc[mi][ni] = __builtin_amdgcn_mfma_f32_16x16x32_bf16(Af[mi][1], Bf[ni][1], acc[mi][ni], 0, 0, 0);
      }
    POST_MFMA();

    // ---- phase 4: stage A-half1(kt+2); counted vmcnt lands tile kt+1; MFMA (1,1)
    if (kt + 2 < NT) STAGE(ALDS(bsel, 1), As1 + k2);
    if (kt < NT - 2) { asm volatile("s_waitcnt vmcnt(4)" ::: "memory"); }
    else             { asm volatile("s_waitcnt vmcnt(0)" ::: "memory"); }
    PRE_MFMA();
#pragma unroll
    for (int mi = 4; mi < 8; ++mi)
#pragma unroll
      for (int ni = 2; ni < 4; ++ni) {
        acc[mi][ni] = __builtin_amdgcn_mfma_f32_16x16x32_bf16(Af[mi][0], Bf[ni][0], acc[mi][ni], 0, 0, 0);
        acc[mi][ni] = __builtin_amdgcn_mfma_f32_16x16x32_bf16(Af[mi][1], Bf[ni][1], acc[mi][ni], 0, 0, 0);
      }
    POST_MFMA();
  }

  // ---- epilogue: C[row][col] bf16; row = m0+wm*128+mi*16+fq*4+j, col = n0+wn*64+ni*16+fr
  unsigned short* Cg = Call + (long)bz * cPerB;
  const int colBase = n0 + wn * 64 + fr;
  const int rowBase = m0 + wm * 128 + fq * 4;
#pragma unroll
  for (int mi = 0; mi < 8; ++mi)
#pragma unroll
    for (int ni = 0; ni < 4; ++ni) {
      const int col = colBase + ni * 16;
      const int rw = rowBase + mi * 16;
#pragma unroll
      for (int j = 0; j < 4; ++j)
        Cg[(size_t)(rw + j) * Nn + col] = f2b(acc[mi][ni][j]);
    }

  if (STATS) {
    const int e = top1[bz];
#pragma unroll
    for (int ni = 0; ni < 4; ++ni) {
      float s1 = 0.f, s2 = 0.f;
#pragma unroll
      for (int mi = 0; mi < 8; ++mi)
#pragma unroll
        for (int j = 0; j < 4; ++j) { float v = acc[mi][ni][j]; s1 += v; s2 += v * v; }
      s1 += __shfl_xor(s1, 16); s2 += __shfl_xor(s2, 16);
      s1 += __shfl_xor(s1, 32); s2 += __shfl_xor(s2, 32);
      if (fq == 0) {
        const int col = colBase + ni * 16;
        atomicAdd(&ssum[e * Hc + col], s1);
        atomicAdd(&ssq[e * Hc + col], s2);
      }
    }
  }
#undef STAGE
#undef ALDS
#undef BLDS
}

// ---------------- BN finalize: scale/shift per [E,H] ----------------
__global__ void k_bnfin(const float* __restrict__ ssum, const float* __restrict__ ssq,
                        const int* __restrict__ top1,
                        const float* __restrict__ gamma, const float* __restrict__ beta,
                        float* __restrict__ scale, float* __restrict__ shift) {
  const int i = blockIdx.x * 256 + threadIdx.x;  // E*H = 4096
  const int e = i >> 10;
  int c = 0;
  for (int j = 0; j < Bc; ++j) c += (top1[j] == e) ? 1 : 0;
  float cf = fmaxf((float)c * (float)Nc, 1.0f);
  float mean = ssum[i] / cf;
  float var = ssq[i] / cf - mean * mean;
  float inv = rsqrtf(var + EPS);
  float sc = gamma[i] * inv;
  scale[i] = sc;
  shift[i] = beta[i] - mean * sc;
}

// ---------------- apply BN + ReLU, bf16 -> fp32 out ----------------
__global__ void k_apply(const unsigned short* __restrict__ ob,
                        const float* __restrict__ scale, const float* __restrict__ shift,
                        const int* __restrict__ top1, float* __restrict__ y) {
  size_t idx = ((size_t)blockIdx.x * 256 + threadIdx.x) * 4;
  const int b = (int)(idx >> 19);     // N*H = 2^19
  const int k = (int)(idx & 1023);    // H = 1024
  const int e = top1[b];
  us4 u = *(const us4*)(ob + idx);
  float4 sc = *(const float4*)(scale + e * Hc + k);
  float4 sh = *(const float4*)(shift + e * Hc + k);
  float4 r;
  r.x = fmaxf(fmaf(b2f(u.x), sc.x, sh.x), 0.f);
  r.y = fmaxf(fmaf(b2f(u.y), sc.y, sh.y), 0.f);
  r.z = fmaxf(fmaf(b2f(u.z), sc.z, sh.z), 0.f);
  r.w = fmaxf(fmaf(b2f(u.w), sc.w, sh.w), 0.f);
  *(float4*)(y + idx) = r;
}

extern "C" void kernel_launch(void* const* d_in, const int* in_sizes, int n_in,
                              void* d_out, int out_size, void* d_ws, size_t ws_size,
                              hipStream_t stream) {
  const float* x     = (const float*)d_in[0];
  const float* adj   = (const float*)d_in[1];
  const float* rw    = (const float*)d_in[2];
  const float* rb    = (const float*)d_in[3];
  const float* ew    = (const float*)d_in[4];
  const float* gamma = (const float*)d_in[5];
  const float* beta  = (const float*)d_in[6];
  float* out = (float*)d_out;
  char* ws = (char*)d_ws;

  // workspace layout (bytes)
  float* xm    = (float*)(ws + 0);          // 262144
  float* ssum  = (float*)(ws + 262144);     // 16384
  float* ssq   = (float*)(ws + 278528);     // 16384
  float* scale = (float*)(ws + 294912);     // 16384
  float* shift = (float*)(ws + 311296);     // 16384
  int*   top1  = (int*)  (ws + 327680);     // 256
  unsigned short* xb   = (unsigned short*)(ws + 327936);     // 67108864 (aliased by outb)
  unsigned short* adjb = (unsigned short*)(ws + 67436800);   // 33554432
  unsigned short* wT   = (unsigned short*)(ws + 100991232);  // 8388608
  unsigned short* supT = (unsigned short*)(ws + 109379840);  // 67108864
  unsigned short* outb = xb;  // x_bf16 dead after GEMM1 -> reuse for out_bf16

  hipMemsetAsync(ws, 0, 294912, stream);  // zero xm + ssum + ssq

  k_xconv<<<Bc * 8, 256, 0, stream>>>(x, xb, xm);
  k_adjconv<<<(Bc * Nc * Nc) / 1024, 256, 0, stream>>>(adj, adjb);
  k_wtrans<<<dim3(Hc / 32, Hc / 32, Ec), dim3(32, 8), 0, stream>>>(ew, wT);
  k_router<<<Bc, 256, 0, stream>>>(xm, rw, rb, top1);

  // GEMM1: supT[b][k][n] = sum_h wT[e][k][h] * x[b][n][h];  M=1024 (NX=4), Nn=512 (NY=2), K=1024
  gemm8<4, 2, false><<<512, 512, 0, stream>>>(
      wT, xb, supT, top1, nullptr, nullptr,
      Nc, Hc, 0L, (long)Nc * Hc, (long)Hc * Nc, (long)Hc * Hc);

  // GEMM2: out[b][n][k] = sum_m adj[b][n][m] * supT[b][k][m];  M=512 (NX=2), Nn=1024 (NY=4), K=512
  gemm8<2, 4, true><<<512, 512, 0, stream>>>(
      adjb, supT, outb, top1, ssum, ssq,
      Hc, Nc, (long)Nc * Nc, (long)Hc * Nc, (long)Nc * Hc, 0L);

  k_bnfin<<<(Ec * Hc) / 256, 256, 0, stream>>>(ssum, ssq, top1, gamma, beta, scale, shift);
  k_apply<<<(Bc * Nc * Hc) / 1024, 256, 0, stream>>>(outb, scale, shift, top1, out);
}